// Round 11
// baseline (656.784 us; speedup 1.0000x reference)
//
#include <hip/hip_runtime.h>

#define HID 256
#define VOC 50257
#define NTOK 4096
#define NCT3 393                  // ceil(VOC / 128)
#define CG 8                      // column groups (== XCDs)
#define TN 128                    // cols per iteration
#define LN_EPS 1e-3f
#define PROB_ELEMS 205852672      // 4096 * 50257

typedef __attribute__((ext_vector_type(8))) short bf16x8;
typedef __attribute__((ext_vector_type(4))) float f32x4;
typedef __attribute__((ext_vector_type(16))) float f32x16;

__device__ inline unsigned short f2bf(float f) {
    unsigned int u = __builtin_bit_cast(unsigned int, f);
    unsigned int r = u + 0x7FFFu + ((u >> 16) & 1u);
    return (unsigned short)(r >> 16);
}
__device__ inline float bf2f(unsigned short b) {
    unsigned int u = ((unsigned int)b) << 16;
    return __builtin_bit_cast(float, u);
}

// ---------------------------------------------------------------- conv f32->bf16 (emb)
__global__ void conv_f32_bf16(const float* __restrict__ src,
                              unsigned short* __restrict__ dst, int n4) {
    int i = blockIdx.x * blockDim.x + threadIdx.x;
    int stride = gridDim.x * blockDim.x;
    for (; i < n4; i += stride) {
        float4 v = reinterpret_cast<const float4*>(src)[i];
        ushort4 o;
        o.x = f2bf(v.x); o.y = f2bf(v.y); o.z = f2bf(v.z); o.w = f2bf(v.w);
        reinterpret_cast<ushort4*>(dst)[i] = o;
    }
}

// ---------------------------------------------------------------- W transpose: W[e][k][h] f32 -> Wt[e*256+h][k] bf16
__global__ __launch_bounds__(256) void wt_transpose(
    const float* __restrict__ Wsh, const float* __restrict__ Wsp,
    unsigned short* __restrict__ Wtbf) {
    __shared__ float t[64][65];
    int gcol0 = blockIdx.x * 64;
    int k0 = blockIdx.y * 64;
    int e = gcol0 >> 8, h0 = gcol0 & 255;
    const float* Wp = (e < 2) ? (Wsh + e * 65536) : (Wsp + (e - 2) * 65536);
    int tid = threadIdx.x;
#pragma unroll
    for (int i = 0; i < 16; ++i) {
        int id = tid + i * 256;
        int k = id >> 6, h = id & 63;
        t[k][h] = Wp[(k0 + k) * 256 + h0 + h];
    }
    __syncthreads();
#pragma unroll
    for (int i = 0; i < 4; ++i) {
        int id = tid + i * 256;
        int h = id >> 4, kq = id & 15;
        ushort4 o;
        o.x = f2bf(t[kq * 4 + 0][h]); o.y = f2bf(t[kq * 4 + 1][h]);
        o.z = f2bf(t[kq * 4 + 2][h]); o.w = f2bf(t[kq * 4 + 3][h]);
        *reinterpret_cast<ushort4*>(Wtbf + (size_t)(gcol0 + h) * 256 + k0 + kq * 4) = o;
    }
}

// ---------------------------------------------------------------- expert GEMM (fused x f32->bf16 conversion)
__global__ __launch_bounds__(256) void expert_gemm(
    const float* __restrict__ x,
    const unsigned short* __restrict__ Wtbf,
    const float* __restrict__ bsh, const float* __restrict__ bsp,
    float* __restrict__ cexp) {
    __shared__ unsigned short sA[64 * 256];
    __shared__ unsigned short sB[128 * 256];
    int bid = blockIdx.x;
    int rt = bid & 63;
    int ct = bid >> 6;
    int row0 = rt * 64, col0 = ct * 128;
    int tid = threadIdx.x;

#pragma unroll
    for (int i = 0; i < 8; ++i) {
        int id = tid + i * 256;
        int r = id >> 5, c = id & 31;
        const float* xr = x + (size_t)(row0 + r) * 256 + c * 8;
        float4 v0 = *reinterpret_cast<const float4*>(xr);
        float4 v1 = *reinterpret_cast<const float4*>(xr + 4);
        bf16x8 o;
        o[0] = (short)f2bf(v0.x); o[1] = (short)f2bf(v0.y);
        o[2] = (short)f2bf(v0.z); o[3] = (short)f2bf(v0.w);
        o[4] = (short)f2bf(v1.x); o[5] = (short)f2bf(v1.y);
        o[6] = (short)f2bf(v1.z); o[7] = (short)f2bf(v1.w);
        *reinterpret_cast<bf16x8*>(sA + r * 256 + ((c ^ (r & 7)) * 8)) = o;
    }
#pragma unroll
    for (int i = 0; i < 16; ++i) {
        int id = tid + i * 256;
        int j = id >> 5, c = id & 31;
        bf16x8 v = *reinterpret_cast<const bf16x8*>(Wtbf + (size_t)(col0 + j) * 256 + c * 8);
        *reinterpret_cast<bf16x8*>(sB + j * 256 + ((c ^ (j & 7)) * 8)) = v;
    }
    __syncthreads();

    int lane = tid & 63, wave = tid >> 6;
    int wcol = wave * 32;
    int lrow = lane & 15, g = lane >> 4;
    f32x4 zero4 = {0.f, 0.f, 0.f, 0.f};
    f32x4 acc[4][2];
#pragma unroll
    for (int mf = 0; mf < 4; ++mf)
#pragma unroll
        for (int nf = 0; nf < 2; ++nf) acc[mf][nf] = zero4;

#pragma unroll
    for (int ks = 0; ks < 8; ++ks) {
        int kc = ks * 4 + g;
        bf16x8 a[4], b[2];
#pragma unroll
        for (int mf = 0; mf < 4; ++mf) {
            int r = mf * 16 + lrow;
            a[mf] = *reinterpret_cast<const bf16x8*>(sA + r * 256 + ((kc ^ (r & 7)) * 8));
        }
#pragma unroll
        for (int nf = 0; nf < 2; ++nf) {
            int j = wcol + nf * 16 + lrow;
            b[nf] = *reinterpret_cast<const bf16x8*>(sB + j * 256 + ((kc ^ (j & 7)) * 8));
        }
#pragma unroll
        for (int mf = 0; mf < 4; ++mf)
#pragma unroll
            for (int nf = 0; nf < 2; ++nf)
                acc[mf][nf] = __builtin_amdgcn_mfma_f32_16x16x32_bf16(a[mf], b[nf], acc[mf][nf], 0, 0, 0);
    }

#pragma unroll
    for (int nf = 0; nf < 2; ++nf) {
        int col = col0 + wcol + nf * 16 + lrow;
        int e = col >> 8, h = col & 255;
        float bias = (e < 2) ? bsh[e * 256 + h] : bsp[(e - 2) * 256 + h];
#pragma unroll
        for (int mf = 0; mf < 4; ++mf)
#pragma unroll
            for (int r = 0; r < 4; ++r) {
                int row = row0 + mf * 16 + g * 4 + r;
                cexp[(size_t)row * 2560 + col] = acc[mf][nf][r] + bias;
            }
    }
}

// ---------------------------------------------------------------- gates + combine + LN + residual
__global__ __launch_bounds__(256) void combine_ln(
    const float* __restrict__ x, const int* __restrict__ xb,
    const float* __restrict__ wg, const float* __restrict__ cexp,
    const float* __restrict__ gamma, const float* __restrict__ beta,
    unsigned short* __restrict__ ebf) {
    __shared__ float sx[256];
    __shared__ float sg[4];
    __shared__ float rs[4], rq[4];
    int n = blockIdx.x, h = threadIdx.x;
    float xv = x[n * 256 + h];
    sx[h] = xv;
    __syncthreads();
    int xbn = xb[n];
    float eo;
    if (xbn == 0) {
        eo = beta[h] + xv;
    } else {
        int t = xbn - 1;
        int wv = h >> 6, lane = h & 63;
        float p = 0.f;
        const float* wgt = wg + t * 1024;
#pragma unroll
        for (int i = 0; i < 4; ++i) {
            int d = lane * 4 + i;
            p += sx[d] * wgt[d * 4 + wv];
        }
#pragma unroll
        for (int off = 32; off; off >>= 1) p += __shfl_down(p, off);
        if (lane == 0) sg[wv] = p;
        __syncthreads();
        float g0 = sg[0], g1 = sg[1], g2 = sg[2], g3 = sg[3];
        float mx = fmaxf(fmaxf(g0, g1), fmaxf(g2, g3));
        float e0 = __expf(g0 - mx), e1 = __expf(g1 - mx);
        float e2 = __expf(g2 - mx), e3 = __expf(g3 - mx);
        float inv = 1.f / (e0 + e1 + e2 + e3);
        const float* cr = cexp + (size_t)n * 2560;
        float o = (e0 * cr[h] + e1 * cr[256 + h] +
                   e2 * cr[512 + t * 512 + h] + e3 * cr[768 + t * 512 + h]) * inv;
        float s = o, q = o * o;
#pragma unroll
        for (int off = 32; off; off >>= 1) { s += __shfl_down(s, off); q += __shfl_down(q, off); }
        if (lane == 0) { rs[wv] = s; rq[wv] = q; }
        __syncthreads();
        float mu = (rs[0] + rs[1] + rs[2] + rs[3]) * (1.f / 256.f);
        float ex2 = (rq[0] + rq[1] + rq[2] + rq[3]) * (1.f / 256.f);
        float var = ex2 - mu * mu;
        eo = gamma[h] * (o - mu) * rsqrtf(var + LN_EPS) + beta[h] + xv;
    }
    ebf[n * 256 + h] = f2bf(eo);
}

// ---------------------------------------------------------------- vocab GEMM v11 (v3 + counted-vmcnt store pipeline)
// Persistent: 32 row-tiles x 8 col-groups = 256 blocks, 512 threads (8 waves).
// A in registers; B streamed through 2x64KB LDS dbuf via global_load_lds.
// PASS 1 pipeline per iteration (T4 counted-vmcnt, raw s_barrier):
//   1. stage(t+1)           (8 global_load_lds  -- oldest in FIFO)
//   2. store pend of t-1    (32 scalar stores   -- newer, stay in flight)
//   3. MFMA tile t          (LDS only)
//   4. s_waitcnt vmcnt(32)  (stage loads retired; stores keep draining)
//   5. __builtin_amdgcn_s_barrier()   (raw: no auto vmcnt(0) drain)
//   6. epilogue: pend = exp(acc+bias)*invd  (in-place in acc regs)
// PASS 0 identical but vmcnt(0) (no stores) and es accumulation.
template <int PASS>
__global__ __launch_bounds__(512, 2) void big_gemm(
    const unsigned short* __restrict__ ebf,
    const unsigned short* __restrict__ embbf,
    const float* __restrict__ vbias,
    float* __restrict__ psum,
    const float* __restrict__ denom,
    float* __restrict__ prob) {
    __shared__ unsigned short sB[2][TN * 256];   // 128 KB

    int bid = blockIdx.x;
    int rt = bid >> 3;           // 32 row tiles
    int cg = bid & 7;            // col group == XCD
    int row0 = rt * 128;
    int tid = threadIdx.x;
    int wave = tid >> 6, lane = tid & 63;
    int l31 = lane & 31, hi = lane >> 5;
    int wr = wave >> 2, wc = wave & 3;
    int nmy = (NCT3 - cg + CG - 1) / CG;   // tiles ct = cg, cg+8, ...

    // ---- A into registers
    bf16x8 a[2][16];
    {
        const unsigned short* ab =
            ebf + (size_t)(row0 + wr * 64 + l31) * 256 + hi * 8;
#pragma unroll
        for (int mf = 0; mf < 2; ++mf)
#pragma unroll
            for (int ks = 0; ks < 16; ++ks)
                a[mf][ks] = *reinterpret_cast<const bf16x8*>(ab + mf * 32 * 256 + ks * 16);
    }

    // ---- stage helper: LDS col-major [col][256k], 16B chunk swizzle ^ (col&7)
    auto stage = [&](int ct, int buf) {
        int col0 = ct * TN;
#pragma unroll
        for (int i = 0; i < 8; ++i) {
            int col = i * 16 + wave * 2 + hi;
            int gcol = col0 + col; if (gcol >= VOC) gcol = VOC - 1;
            const unsigned short* src =
                embbf + (size_t)gcol * 256 + ((l31 ^ (col & 7)) * 8);
            unsigned short* dst = (unsigned short*)sB[buf] + (size_t)(i * 512 + wave * 64) * 8;
            __builtin_amdgcn_global_load_lds(
                (const __attribute__((address_space(1))) void*)src,
                (__attribute__((address_space(3))) void*)dst, 16, 0, 0);
        }
    };

    stage(cg, 0);
    asm volatile("s_waitcnt vmcnt(0)" ::: "memory");
    __builtin_amdgcn_s_barrier();

    float invd[2][16];
    if (PASS == 1) {
#pragma unroll
        for (int mf = 0; mf < 2; ++mf)
#pragma unroll
            for (int r = 0; r < 16; ++r) {
                int row = row0 + wr * 64 + mf * 32 + (r & 3) + 8 * (r >> 2) + 4 * hi;
                invd[mf][r] = 1.f / denom[row];
            }
    }
    float es[2][16];
    if (PASS == 0) {
#pragma unroll
        for (int mf = 0; mf < 2; ++mf)
#pragma unroll
            for (int r = 0; r < 16; ++r) es[mf][r] = 0.f;
    }

    f32x16 zz = {0.f,0.f,0.f,0.f,0.f,0.f,0.f,0.f,0.f,0.f,0.f,0.f,0.f,0.f,0.f,0.f};
    f32x16 c0p = zz, c1p = zz;    // pend prob values (PASS 1)
    int gcp = VOC;                // invalid -> no store on first iter

    for (int it = 0; it < nmy; ++it) {
        int ct = cg + it * CG;
        // 1. stage next tile FIRST (loads oldest in VMEM FIFO)
        if (it + 1 < nmy) stage(ct + CG, (it + 1) & 1);

        // 2. deferred stores of previous tile (newer than the stage loads)
        if (PASS == 1) {
            asm volatile("" ::: "memory");   // pin program order: loads before stores
            if (gcp < VOC) {
#pragma unroll
                for (int r = 0; r < 16; ++r) {
                    int rowr = row0 + wr * 64 + (r & 3) + 8 * (r >> 2) + 4 * hi;
                    prob[(size_t)rowr * VOC + gcp] = c0p[r];
                    prob[(size_t)(rowr + 32) * VOC + gcp] = c1p[r];
                }
            }
        }

        int gc = ct * TN + wc * 32 + l31;
        float bvb = (gc < VOC) ? vbias[gc] : -1e4f;

        // 3. compute (LDS only)
        const unsigned short* sBc = (const unsigned short*)sB[it & 1];
        int bcol = wc * 32 + l31;
        f32x16 c0 = zz, c1 = zz;
#pragma unroll
        for (int ks = 0; ks < 16; ++ks) {
            int kc = ks * 2 + hi;
            bf16x8 b = *reinterpret_cast<const bf16x8*>(
                sBc + bcol * 256 + ((kc ^ (bcol & 7)) * 8));
            c0 = __builtin_amdgcn_mfma_f32_32x32x16_bf16(a[0][ks], b, c0, 0, 0, 0);
            c1 = __builtin_amdgcn_mfma_f32_32x32x16_bf16(a[1][ks], b, c1, 0, 0, 0);
        }

        // 4. counted wait: stage loads retired, stores stay in flight
        if (PASS == 0) asm volatile("s_waitcnt vmcnt(0)" ::: "memory");
        else           asm volatile("s_waitcnt vmcnt(32)" ::: "memory");
        // 5. raw barrier (no compiler-forced vmcnt(0) drain)
        __builtin_amdgcn_s_barrier();

        // 6. epilogue
        if (PASS == 0) {
#pragma unroll
            for (int r = 0; r < 16; ++r) {
                es[0][r] += __expf(c0[r] + bvb);
                es[1][r] += __expf(c1[r] + bvb);
            }
        } else {
#pragma unroll
            for (int r = 0; r < 16; ++r) {
                c0p[r] = __expf(c0[r] + bvb) * invd[0][r];
                c1p[r] = __expf(c1[r] + bvb) * invd[1][r];
            }
            gcp = gc;
        }
    }

    if (PASS == 0) {
#pragma unroll
        for (int mf = 0; mf < 2; ++mf)
#pragma unroll
            for (int r = 0; r < 16; ++r) {
                float v = es[mf][r];
#pragma unroll
                for (int off = 1; off < 32; off <<= 1) v += __shfl_xor(v, off);
                if (l31 == 0) {
                    int row = row0 + wr * 64 + mf * 32 + (r & 3) + 8 * (r >> 2) + 4 * hi;
                    psum[(size_t)row * 32 + cg * 4 + wc] = v;
                }
            }
    } else {
        // flush last tile's pend
        if (gcp < VOC) {
#pragma unroll
            for (int r = 0; r < 16; ++r) {
                int rowr = row0 + wr * 64 + (r & 3) + 8 * (r >> 2) + 4 * hi;
                prob[(size_t)rowr * VOC + gcp] = c0p[r];
                prob[(size_t)(rowr + 32) * VOC + gcp] = c1p[r];
            }
        }
    }
}

// ---------------------------------------------------------------- finalize: denom + loss
__global__ __launch_bounds__(64) void finalize_k(
    const float* __restrict__ psum,
    const unsigned short* __restrict__ ebf, const unsigned short* __restrict__ embbf,
    const float* __restrict__ vbias, const int* __restrict__ labels,
    float* __restrict__ denom, float* __restrict__ loss) {
    int n = blockIdx.x, lane = threadIdx.x;
    float s = (lane < 32) ? psum[(size_t)n * 32 + lane] : 0.f;
#pragma unroll
    for (int off = 1; off < 32; off <<= 1) s += __shfl_xor(s, off);
    int lf = labels[n];
    const unsigned short* ev = ebf + n * 256;
    const unsigned short* mv = embbf + (size_t)lf * 256;
    float p = 0.f;
#pragma unroll
    for (int i = 0; i < 4; ++i) p += bf2f(ev[lane * 4 + i]) * bf2f(mv[lane * 4 + i]);
#pragma unroll
    for (int off = 1; off < 64; off <<= 1) p += __shfl_xor(p, off);
    if (lane == 0) {
        denom[n] = s;
        loss[n] = logf(s) - (p + vbias[lf]);
    }
}

// ---------------------------------------------------------------- launch
extern "C" void kernel_launch(void* const* d_in, const int* in_sizes, int n_in,
                              void* d_out, int out_size, void* d_ws, size_t ws_size,
                              hipStream_t stream) {
    const float* x      = (const float*)d_in[0];
    const int*   labels = (const int*)d_in[1];
    const int*   xb     = (const int*)d_in[2];
    const float* Wsh    = (const float*)d_in[3];
    const float* bsh    = (const float*)d_in[4];
    const float* Wsp    = (const float*)d_in[5];
    const float* bsp    = (const float*)d_in[6];
    const float* wg     = (const float*)d_in[7];
    const float* vbias  = (const float*)d_in[8];
    const float* emb    = (const float*)d_in[9];
    const float* gamma  = (const float*)d_in[10];
    const float* beta   = (const float*)d_in[11];

    char* ws = (char*)d_ws;
    unsigned short* embbf = (unsigned short*)(ws + 2097152);    // 25,731,584
    unsigned short* Wtbf  = (unsigned short*)(ws + 27828736);   // 1,310,720
    float* cexp           = (float*)(ws + 29360128);            // 41,943,040
    unsigned short* ebf   = (unsigned short*)(ws + 71303168);   // 2,097,152
    float* psum           = (float*)(ws + 73400320);            // 524,288
    float* denom          = (float*)(ws + 73924608);            // 16,384

    float* prob = (float*)d_out;
    float* loss = prob + PROB_ELEMS;

    conv_f32_bf16<<<dim3(2048), dim3(256), 0, stream>>>(emb, embbf, VOC * HID / 4);
    wt_transpose<<<dim3(40, 4), dim3(256), 0, stream>>>(Wsh, Wsp, Wtbf);
    expert_gemm<<<dim3(64 * 20), dim3(256), 0, stream>>>(x, Wtbf, bsh, bsp, cexp);
    combine_ln<<<dim3(NTOK), dim3(256), 0, stream>>>(x, xb, wg, cexp, gamma, beta, ebf);
    big_gemm<0><<<dim3(256), dim3(512), 0, stream>>>(ebf, embbf, vbias, psum, nullptr, nullptr);
    finalize_k<<<dim3(NTOK), dim3(64), 0, stream>>>(psum, ebf, embbf, vbias, labels, denom, loss);
    big_gemm<1><<<dim3(256), dim3(512), 0, stream>>>(ebf, embbf, vbias, nullptr, denom, prob);
}

// Round 12
// 533.550 us; speedup vs baseline: 1.2310x; 1.2310x over previous
//
#include <hip/hip_runtime.h>

#define HID 256
#define VOC 50257
#define NTOK 4096
#define NCT3 393                  // ceil(VOC / 128)
#define CG 8                      // column groups (== XCDs)
#define TN 128                    // cols per iteration
#define LN_EPS 1e-3f
#define PROB_ELEMS 205852672      // 4096 * 50257

typedef __attribute__((ext_vector_type(8))) short bf16x8;
typedef __attribute__((ext_vector_type(4))) float f32x4;
typedef __attribute__((ext_vector_type(16))) float f32x16;

__device__ inline unsigned short f2bf(float f) {
    unsigned int u = __builtin_bit_cast(unsigned int, f);
    unsigned int r = u + 0x7FFFu + ((u >> 16) & 1u);
    return (unsigned short)(r >> 16);
}
__device__ inline float bf2f(unsigned short b) {
    unsigned int u = ((unsigned int)b) << 16;
    return __builtin_bit_cast(float, u);
}

// ---------------------------------------------------------------- prep: emb f32->bf16 AND W transpose, one launch
// blocks [0,160): wt_transpose tiles; blocks [160, 2208): emb conversion (grid-stride)
__global__ __launch_bounds__(256) void prep_kernel(
    const float* __restrict__ emb, const float* __restrict__ Wsh,
    const float* __restrict__ Wsp,
    unsigned short* __restrict__ embbf, unsigned short* __restrict__ Wtbf) {
    __shared__ float t[64][65];
    int tid = threadIdx.x;
    if (blockIdx.x < 160) {
        int bx = blockIdx.x % 40, by = blockIdx.x / 40;
        int gcol0 = bx * 64;
        int k0 = by * 64;
        int e = gcol0 >> 8, h0 = gcol0 & 255;
        const float* Wp = (e < 2) ? (Wsh + e * 65536) : (Wsp + (e - 2) * 65536);
#pragma unroll
        for (int i = 0; i < 16; ++i) {
            int id = tid + i * 256;
            int k = id >> 6, h = id & 63;
            t[k][h] = Wp[(k0 + k) * 256 + h0 + h];
        }
        __syncthreads();
#pragma unroll
        for (int i = 0; i < 4; ++i) {
            int id = tid + i * 256;
            int h = id >> 4, kq = id & 15;
            ushort4 o;
            o.x = f2bf(t[kq * 4 + 0][h]); o.y = f2bf(t[kq * 4 + 1][h]);
            o.z = f2bf(t[kq * 4 + 2][h]); o.w = f2bf(t[kq * 4 + 3][h]);
            *reinterpret_cast<ushort4*>(Wtbf + (size_t)(gcol0 + h) * 256 + k0 + kq * 4) = o;
        }
    } else {
        const int n4 = VOC * HID / 4;
        int i = (blockIdx.x - 160) * 256 + tid;
        int stride = (gridDim.x - 160) * 256;
        for (; i < n4; i += stride) {
            float4 v = reinterpret_cast<const float4*>(emb)[i];
            ushort4 o;
            o.x = f2bf(v.x); o.y = f2bf(v.y); o.z = f2bf(v.z); o.w = f2bf(v.w);
            reinterpret_cast<ushort4*>(embbf)[i] = o;
        }
    }
}

// ---------------------------------------------------------------- expert GEMM (64x64 tiles, 2 blocks/CU, fused x conv)
__global__ __launch_bounds__(256) void expert_gemm(
    const float* __restrict__ x,
    const unsigned short* __restrict__ Wtbf,
    const float* __restrict__ bsh, const float* __restrict__ bsp,
    float* __restrict__ cexp) {
    __shared__ unsigned short sA[64 * 256];   // 32 KB
    __shared__ unsigned short sB[64 * 256];   // 32 KB
    int bid = blockIdx.x;
    int rt = bid & 63;
    int ct = bid >> 6;            // 0..39
    int row0 = rt * 64, col0 = ct * 64;
    int tid = threadIdx.x;

#pragma unroll
    for (int i = 0; i < 8; ++i) {
        int id = tid + i * 256;
        int r = id >> 5, c = id & 31;
        const float* xr = x + (size_t)(row0 + r) * 256 + c * 8;
        float4 v0 = *reinterpret_cast<const float4*>(xr);
        float4 v1 = *reinterpret_cast<const float4*>(xr + 4);
        bf16x8 o;
        o[0] = (short)f2bf(v0.x); o[1] = (short)f2bf(v0.y);
        o[2] = (short)f2bf(v0.z); o[3] = (short)f2bf(v0.w);
        o[4] = (short)f2bf(v1.x); o[5] = (short)f2bf(v1.y);
        o[6] = (short)f2bf(v1.z); o[7] = (short)f2bf(v1.w);
        *reinterpret_cast<bf16x8*>(sA + r * 256 + ((c ^ (r & 7)) * 8)) = o;
    }
#pragma unroll
    for (int i = 0; i < 8; ++i) {
        int id = tid + i * 256;
        int j = id >> 5, c = id & 31;
        bf16x8 v = *reinterpret_cast<const bf16x8*>(Wtbf + (size_t)(col0 + j) * 256 + c * 8);
        *reinterpret_cast<bf16x8*>(sB + j * 256 + ((c ^ (j & 7)) * 8)) = v;
    }
    __syncthreads();

    int lane = tid & 63, wave = tid >> 6;
    int wcol = wave * 16;         // wave covers cols wcol..wcol+16 of the 64
    int lrow = lane & 15, g = lane >> 4;
    f32x4 zero4 = {0.f, 0.f, 0.f, 0.f};
    f32x4 acc[4];
#pragma unroll
    for (int mf = 0; mf < 4; ++mf) acc[mf] = zero4;

#pragma unroll
    for (int ks = 0; ks < 8; ++ks) {
        int kc = ks * 4 + g;
        int j = wcol + lrow;
        bf16x8 b = *reinterpret_cast<const bf16x8*>(sB + j * 256 + ((kc ^ (j & 7)) * 8));
        bf16x8 a[4];
#pragma unroll
        for (int mf = 0; mf < 4; ++mf) {
            int r = mf * 16 + lrow;
            a[mf] = *reinterpret_cast<const bf16x8*>(sA + r * 256 + ((kc ^ (r & 7)) * 8));
        }
#pragma unroll
        for (int mf = 0; mf < 4; ++mf)
            acc[mf] = __builtin_amdgcn_mfma_f32_16x16x32_bf16(a[mf], b, acc[mf], 0, 0, 0);
    }

    {
        int col = col0 + wcol + lrow;
        int e = col >> 8, h = col & 255;
        float bias = (e < 2) ? bsh[e * 256 + h] : bsp[(e - 2) * 256 + h];
#pragma unroll
        for (int mf = 0; mf < 4; ++mf)
#pragma unroll
            for (int r = 0; r < 4; ++r) {
                int row = row0 + mf * 16 + g * 4 + r;
                cexp[(size_t)row * 2560 + col] = acc[mf][r] + bias;
            }
    }
}

// ---------------------------------------------------------------- gates + combine + LN + residual
__global__ __launch_bounds__(256) void combine_ln(
    const float* __restrict__ x, const int* __restrict__ xb,
    const float* __restrict__ wg, const float* __restrict__ cexp,
    const float* __restrict__ gamma, const float* __restrict__ beta,
    unsigned short* __restrict__ ebf) {
    __shared__ float sx[256];
    __shared__ float sg[4];
    __shared__ float rs[4], rq[4];
    int n = blockIdx.x, h = threadIdx.x;
    float xv = x[n * 256 + h];
    sx[h] = xv;
    __syncthreads();
    int xbn = xb[n];
    float eo;
    if (xbn == 0) {
        eo = beta[h] + xv;
    } else {
        int t = xbn - 1;
        int wv = h >> 6, lane = h & 63;
        float p = 0.f;
        const float* wgt = wg + t * 1024;
#pragma unroll
        for (int i = 0; i < 4; ++i) {
            int d = lane * 4 + i;
            p += sx[d] * wgt[d * 4 + wv];
        }
#pragma unroll
        for (int off = 32; off; off >>= 1) p += __shfl_down(p, off);
        if (lane == 0) sg[wv] = p;
        __syncthreads();
        float g0 = sg[0], g1 = sg[1], g2 = sg[2], g3 = sg[3];
        float mx = fmaxf(fmaxf(g0, g1), fmaxf(g2, g3));
        float e0 = __expf(g0 - mx), e1 = __expf(g1 - mx);
        float e2 = __expf(g2 - mx), e3 = __expf(g3 - mx);
        float inv = 1.f / (e0 + e1 + e2 + e3);
        const float* cr = cexp + (size_t)n * 2560;
        float o = (e0 * cr[h] + e1 * cr[256 + h] +
                   e2 * cr[512 + t * 512 + h] + e3 * cr[768 + t * 512 + h]) * inv;
        float s = o, q = o * o;
#pragma unroll
        for (int off = 32; off; off >>= 1) { s += __shfl_down(s, off); q += __shfl_down(q, off); }
        if (lane == 0) { rs[wv] = s; rq[wv] = q; }
        __syncthreads();
        float mu = (rs[0] + rs[1] + rs[2] + rs[3]) * (1.f / 256.f);
        float ex2 = (rq[0] + rq[1] + rq[2] + rq[3]) * (1.f / 256.f);
        float var = ex2 - mu * mu;
        eo = gamma[h] * (o - mu) * rsqrtf(var + LN_EPS) + beta[h] + xv;
    }
    ebf[n * 256 + h] = f2bf(eo);
}

// ---------------------------------------------------------------- vocab GEMM v3 (best-known; untouched)
template <int PASS>
__global__ __launch_bounds__(512, 2) void big_gemm(
    const unsigned short* __restrict__ ebf,
    const unsigned short* __restrict__ embbf,
    const float* __restrict__ vbias,
    float* __restrict__ psum,
    const float* __restrict__ denom,
    float* __restrict__ prob) {
    __shared__ unsigned short sB[2][TN * 256];   // 128 KB

    int bid = blockIdx.x;
    int rt = bid >> 3;           // 32 row tiles
    int cg = bid & 7;            // col group == XCD
    int row0 = rt * 128;
    int tid = threadIdx.x;
    int wave = tid >> 6, lane = tid & 63;
    int l31 = lane & 31, hi = lane >> 5;
    int wr = wave >> 2, wc = wave & 3;
    int nmy = (NCT3 - cg + CG - 1) / CG;   // tiles ct = cg, cg+8, ...

    bf16x8 a[2][16];
    {
        const unsigned short* ab =
            ebf + (size_t)(row0 + wr * 64 + l31) * 256 + hi * 8;
#pragma unroll
        for (int mf = 0; mf < 2; ++mf)
#pragma unroll
            for (int ks = 0; ks < 16; ++ks)
                a[mf][ks] = *reinterpret_cast<const bf16x8*>(ab + mf * 32 * 256 + ks * 16);
    }

    auto stage = [&](int ct, int buf) {
        int col0 = ct * TN;
#pragma unroll
        for (int i = 0; i < 8; ++i) {
            int col = i * 16 + wave * 2 + hi;
            int gcol = col0 + col; if (gcol >= VOC) gcol = VOC - 1;
            const unsigned short* src =
                embbf + (size_t)gcol * 256 + ((l31 ^ (col & 7)) * 8);
            unsigned short* dst = (unsigned short*)sB[buf] + (size_t)(i * 512 + wave * 64) * 8;
            __builtin_amdgcn_global_load_lds(
                (const __attribute__((address_space(1))) void*)src,
                (__attribute__((address_space(3))) void*)dst, 16, 0, 0);
        }
    };

    stage(cg, 0);
    asm volatile("s_waitcnt vmcnt(0)" ::: "memory");
    __syncthreads();

    float invd[2][16];
    if (PASS == 1) {
#pragma unroll
        for (int mf = 0; mf < 2; ++mf)
#pragma unroll
            for (int r = 0; r < 16; ++r) {
                int row = row0 + wr * 64 + mf * 32 + (r & 3) + 8 * (r >> 2) + 4 * hi;
                invd[mf][r] = 1.f / denom[row];
            }
    }
    float es[2][16];
    if (PASS == 0) {
#pragma unroll
        for (int mf = 0; mf < 2; ++mf)
#pragma unroll
            for (int r = 0; r < 16; ++r) es[mf][r] = 0.f;
    }

    f32x16 zz = {0.f,0.f,0.f,0.f,0.f,0.f,0.f,0.f,0.f,0.f,0.f,0.f,0.f,0.f,0.f,0.f};

    for (int it = 0; it < nmy; ++it) {
        int ct = cg + it * CG;
        if (it + 1 < nmy) stage(ct + CG, (it + 1) & 1);

        int gc = ct * TN + wc * 32 + l31;
        float bvb;
        if (PASS == 0) bvb = (gc < VOC) ? vbias[gc] : -1e4f;
        else           bvb = vbias[(gc < VOC) ? gc : (VOC - 1)];

        const unsigned short* sBc = (const unsigned short*)sB[it & 1];
        int bcol = wc * 32 + l31;
        f32x16 c0 = zz, c1 = zz;
#pragma unroll
        for (int ks = 0; ks < 16; ++ks) {
            int kc = ks * 2 + hi;
            bf16x8 b = *reinterpret_cast<const bf16x8*>(
                sBc + bcol * 256 + ((kc ^ (bcol & 7)) * 8));
            c0 = __builtin_amdgcn_mfma_f32_32x32x16_bf16(a[0][ks], b, c0, 0, 0, 0);
            c1 = __builtin_amdgcn_mfma_f32_32x32x16_bf16(a[1][ks], b, c1, 0, 0, 0);
        }

        asm volatile("s_waitcnt vmcnt(0)" ::: "memory");
        __syncthreads();

        if (PASS == 0) {
#pragma unroll
            for (int r = 0; r < 16; ++r) {
                es[0][r] += __expf(c0[r] + bvb);
                es[1][r] += __expf(c1[r] + bvb);
            }
        } else {
            if (gc < VOC) {
#pragma unroll
                for (int r = 0; r < 16; ++r) {
                    int rowr = row0 + wr * 64 + (r & 3) + 8 * (r >> 2) + 4 * hi;
                    prob[(size_t)rowr * VOC + gc] = __expf(c0[r] + bvb) * invd[0][r];
                    prob[(size_t)(rowr + 32) * VOC + gc] = __expf(c1[r] + bvb) * invd[1][r];
                }
            }
        }
    }

    if (PASS == 0) {
#pragma unroll
        for (int mf = 0; mf < 2; ++mf)
#pragma unroll
            for (int r = 0; r < 16; ++r) {
                float v = es[mf][r];
#pragma unroll
                for (int off = 1; off < 32; off <<= 1) v += __shfl_xor(v, off);
                if (l31 == 0) {
                    int row = row0 + wr * 64 + mf * 32 + (r & 3) + 8 * (r >> 2) + 4 * hi;
                    psum[(size_t)row * 32 + cg * 4 + wc] = v;
                }
            }
    }
}

// ---------------------------------------------------------------- finalize: denom + loss
__global__ __launch_bounds__(64) void finalize_k(
    const float* __restrict__ psum,
    const unsigned short* __restrict__ ebf, const unsigned short* __restrict__ embbf,
    const float* __restrict__ vbias, const int* __restrict__ labels,
    float* __restrict__ denom, float* __restrict__ loss) {
    int n = blockIdx.x, lane = threadIdx.x;
    float s = (lane < 32) ? psum[(size_t)n * 32 + lane] : 0.f;
#pragma unroll
    for (int off = 1; off < 32; off <<= 1) s += __shfl_xor(s, off);
    int lf = labels[n];
    const unsigned short* ev = ebf + n * 256;
    const unsigned short* mv = embbf + (size_t)lf * 256;
    float p = 0.f;
#pragma unroll
    for (int i = 0; i < 4; ++i) p += bf2f(ev[lane * 4 + i]) * bf2f(mv[lane * 4 + i]);
#pragma unroll
    for (int off = 1; off < 64; off <<= 1) p += __shfl_xor(p, off);
    if (lane == 0) {
        denom[n] = s;
        loss[n] = logf(s) - (p + vbias[lf]);
    }
}

// ---------------------------------------------------------------- launch
extern "C" void kernel_launch(void* const* d_in, const int* in_sizes, int n_in,
                              void* d_out, int out_size, void* d_ws, size_t ws_size,
                              hipStream_t stream) {
    const float* x      = (const float*)d_in[0];
    const int*   labels = (const int*)d_in[1];
    const int*   xb     = (const int*)d_in[2];
    const float* Wsh    = (const float*)d_in[3];
    const float* bsh    = (const float*)d_in[4];
    const float* Wsp    = (const float*)d_in[5];
    const float* bsp    = (const float*)d_in[6];
    const float* wg     = (const float*)d_in[7];
    const float* vbias  = (const float*)d_in[8];
    const float* emb    = (const float*)d_in[9];
    const float* gamma  = (const float*)d_in[10];
    const float* beta   = (const float*)d_in[11];

    char* ws = (char*)d_ws;
    unsigned short* embbf = (unsigned short*)(ws + 2097152);    // 25,731,584
    unsigned short* Wtbf  = (unsigned short*)(ws + 27828736);   // 1,310,720
    float* cexp           = (float*)(ws + 29360128);            // 41,943,040
    unsigned short* ebf   = (unsigned short*)(ws + 71303168);   // 2,097,152
    float* psum           = (float*)(ws + 73400320);            // 524,288
    float* denom          = (float*)(ws + 73924608);            // 16,384

    float* prob = (float*)d_out;
    float* loss = prob + PROB_ELEMS;

    prep_kernel<<<dim3(2208), dim3(256), 0, stream>>>(emb, Wsh, Wsp, embbf, Wtbf);
    expert_gemm<<<dim3(64 * 40), dim3(256), 0, stream>>>(x, Wtbf, bsh, bsp, cexp);
    combine_ln<<<dim3(NTOK), dim3(256), 0, stream>>>(x, xb, wg, cexp, gamma, beta, ebf);
    big_gemm<0><<<dim3(256), dim3(512), 0, stream>>>(ebf, embbf, vbias, psum, nullptr, nullptr);
    finalize_k<<<dim3(NTOK), dim3(64), 0, stream>>>(psum, ebf, embbf, vbias, labels, denom, loss);
    big_gemm<1><<<dim3(256), dim3(512), 0, stream>>>(ebf, embbf, vbias, nullptr, denom, prob);
}

// Round 13
// 525.467 us; speedup vs baseline: 1.2499x; 1.0154x over previous
//
#include <hip/hip_runtime.h>

#define HID 256
#define VOC 50257
#define NTOK 4096
#define NCT3 393                  // ceil(VOC / 128)
#define CG 8                      // column groups (== XCDs)
#define TN 128                    // cols per iteration
#define LN_EPS 1e-3f
#define PROB_ELEMS 205852672      // 4096 * 50257

typedef __attribute__((ext_vector_type(8))) short bf16x8;
typedef __attribute__((ext_vector_type(4))) float f32x4;
typedef __attribute__((ext_vector_type(16))) float f32x16;

__device__ inline unsigned short f2bf(float f) {
    unsigned int u = __builtin_bit_cast(unsigned int, f);
    unsigned int r = u + 0x7FFFu + ((u >> 16) & 1u);
    return (unsigned short)(r >> 16);
}
__device__ inline float bf2f(unsigned short b) {
    unsigned int u = ((unsigned int)b) << 16;
    return __builtin_bit_cast(float, u);
}

// ---------------------------------------------------------------- prep: emb f32->bf16 AND W transpose, one launch
__global__ __launch_bounds__(256) void prep_kernel(
    const float* __restrict__ emb, const float* __restrict__ Wsh,
    const float* __restrict__ Wsp,
    unsigned short* __restrict__ embbf, unsigned short* __restrict__ Wtbf) {
    __shared__ float t[64][65];
    int tid = threadIdx.x;
    if (blockIdx.x < 160) {
        int bx = blockIdx.x % 40, by = blockIdx.x / 40;
        int gcol0 = bx * 64;
        int k0 = by * 64;
        int e = gcol0 >> 8, h0 = gcol0 & 255;
        const float* Wp = (e < 2) ? (Wsh + e * 65536) : (Wsp + (e - 2) * 65536);
#pragma unroll
        for (int i = 0; i < 16; ++i) {
            int id = tid + i * 256;
            int k = id >> 6, h = id & 63;
            t[k][h] = Wp[(k0 + k) * 256 + h0 + h];
        }
        __syncthreads();
#pragma unroll
        for (int i = 0; i < 4; ++i) {
            int id = tid + i * 256;
            int h = id >> 4, kq = id & 15;
            ushort4 o;
            o.x = f2bf(t[kq * 4 + 0][h]); o.y = f2bf(t[kq * 4 + 1][h]);
            o.z = f2bf(t[kq * 4 + 2][h]); o.w = f2bf(t[kq * 4 + 3][h]);
            *reinterpret_cast<ushort4*>(Wtbf + (size_t)(gcol0 + h) * 256 + k0 + kq * 4) = o;
        }
    } else {
        const int n4 = VOC * HID / 4;
        int i = (blockIdx.x - 160) * 256 + tid;
        int stride = (gridDim.x - 160) * 256;
        for (; i < n4; i += stride) {
            float4 v = reinterpret_cast<const float4*>(emb)[i];
            ushort4 o;
            o.x = f2bf(v.x); o.y = f2bf(v.y); o.z = f2bf(v.z); o.w = f2bf(v.w);
            reinterpret_cast<ushort4*>(embbf)[i] = o;
        }
    }
}

// ---------------------------------------------------------------- expert GEMM (64x64 tiles, 2 blocks/CU, fused x conv)
__global__ __launch_bounds__(256) void expert_gemm(
    const float* __restrict__ x,
    const unsigned short* __restrict__ Wtbf,
    const float* __restrict__ bsh, const float* __restrict__ bsp,
    float* __restrict__ cexp) {
    __shared__ unsigned short sA[64 * 256];   // 32 KB
    __shared__ unsigned short sB[64 * 256];   // 32 KB
    int bid = blockIdx.x;
    int rt = bid & 63;
    int ct = bid >> 6;            // 0..39
    int row0 = rt * 64, col0 = ct * 64;
    int tid = threadIdx.x;

#pragma unroll
    for (int i = 0; i < 8; ++i) {
        int id = tid + i * 256;
        int r = id >> 5, c = id & 31;
        const float* xr = x + (size_t)(row0 + r) * 256 + c * 8;
        float4 v0 = *reinterpret_cast<const float4*>(xr);
        float4 v1 = *reinterpret_cast<const float4*>(xr + 4);
        bf16x8 o;
        o[0] = (short)f2bf(v0.x); o[1] = (short)f2bf(v0.y);
        o[2] = (short)f2bf(v0.z); o[3] = (short)f2bf(v0.w);
        o[4] = (short)f2bf(v1.x); o[5] = (short)f2bf(v1.y);
        o[6] = (short)f2bf(v1.z); o[7] = (short)f2bf(v1.w);
        *reinterpret_cast<bf16x8*>(sA + r * 256 + ((c ^ (r & 7)) * 8)) = o;
    }
#pragma unroll
    for (int i = 0; i < 8; ++i) {
        int id = tid + i * 256;
        int j = id >> 5, c = id & 31;
        bf16x8 v = *reinterpret_cast<const bf16x8*>(Wtbf + (size_t)(col0 + j) * 256 + c * 8);
        *reinterpret_cast<bf16x8*>(sB + j * 256 + ((c ^ (j & 7)) * 8)) = v;
    }
    __syncthreads();

    int lane = tid & 63, wave = tid >> 6;
    int wcol = wave * 16;
    int lrow = lane & 15, g = lane >> 4;
    f32x4 zero4 = {0.f, 0.f, 0.f, 0.f};
    f32x4 acc[4];
#pragma unroll
    for (int mf = 0; mf < 4; ++mf) acc[mf] = zero4;

#pragma unroll
    for (int ks = 0; ks < 8; ++ks) {
        int kc = ks * 4 + g;
        int j = wcol + lrow;
        bf16x8 b = *reinterpret_cast<const bf16x8*>(sB + j * 256 + ((kc ^ (j & 7)) * 8));
        bf16x8 a[4];
#pragma unroll
        for (int mf = 0; mf < 4; ++mf) {
            int r = mf * 16 + lrow;
            a[mf] = *reinterpret_cast<const bf16x8*>(sA + r * 256 + ((kc ^ (r & 7)) * 8));
        }
#pragma unroll
        for (int mf = 0; mf < 4; ++mf)
            acc[mf] = __builtin_amdgcn_mfma_f32_16x16x32_bf16(a[mf], b, acc[mf], 0, 0, 0);
    }

    {
        int col = col0 + wcol + lrow;
        int e = col >> 8, h = col & 255;
        float bias = (e < 2) ? bsh[e * 256 + h] : bsp[(e - 2) * 256 + h];
#pragma unroll
        for (int mf = 0; mf < 4; ++mf)
#pragma unroll
            for (int r = 0; r < 4; ++r) {
                int row = row0 + mf * 16 + g * 4 + r;
                cexp[(size_t)row * 2560 + col] = acc[mf][r] + bias;
            }
    }
}

// ---------------------------------------------------------------- gates + combine + LN + residual
__global__ __launch_bounds__(256) void combine_ln(
    const float* __restrict__ x, const int* __restrict__ xb,
    const float* __restrict__ wg, const float* __restrict__ cexp,
    const float* __restrict__ gamma, const float* __restrict__ beta,
    unsigned short* __restrict__ ebf) {
    __shared__ float sx[256];
    __shared__ float sg[4];
    __shared__ float rs[4], rq[4];
    int n = blockIdx.x, h = threadIdx.x;
    float xv = x[n * 256 + h];
    sx[h] = xv;
    __syncthreads();
    int xbn = xb[n];
    float eo;
    if (xbn == 0) {
        eo = beta[h] + xv;
    } else {
        int t = xbn - 1;
        int wv = h >> 6, lane = h & 63;
        float p = 0.f;
        const float* wgt = wg + t * 1024;
#pragma unroll
        for (int i = 0; i < 4; ++i) {
            int d = lane * 4 + i;
            p += sx[d] * wgt[d * 4 + wv];
        }
#pragma unroll
        for (int off = 32; off; off >>= 1) p += __shfl_down(p, off);
        if (lane == 0) sg[wv] = p;
        __syncthreads();
        float g0 = sg[0], g1 = sg[1], g2 = sg[2], g3 = sg[3];
        float mx = fmaxf(fmaxf(g0, g1), fmaxf(g2, g3));
        float e0 = __expf(g0 - mx), e1 = __expf(g1 - mx);
        float e2 = __expf(g2 - mx), e3 = __expf(g3 - mx);
        float inv = 1.f / (e0 + e1 + e2 + e3);
        const float* cr = cexp + (size_t)n * 2560;
        float o = (e0 * cr[h] + e1 * cr[256 + h] +
                   e2 * cr[512 + t * 512 + h] + e3 * cr[768 + t * 512 + h]) * inv;
        float s = o, q = o * o;
#pragma unroll
        for (int off = 32; off; off >>= 1) { s += __shfl_down(s, off); q += __shfl_down(q, off); }
        if (lane == 0) { rs[wv] = s; rq[wv] = q; }
        __syncthreads();
        float mu = (rs[0] + rs[1] + rs[2] + rs[3]) * (1.f / 256.f);
        float ex2 = (rq[0] + rq[1] + rq[2] + rq[3]) * (1.f / 256.f);
        float var = ex2 - mu * mu;
        eo = gamma[h] * (o - mu) * rsqrtf(var + LN_EPS) + beta[h] + xv;
    }
    ebf[n * 256 + h] = f2bf(eo);
}

// ---------------------------------------------------------------- vocab GEMM v12 (v3 + CONTIGUOUS per-cg col ranges)
// Persistent: 32 row-tiles x 8 col-groups = 256 blocks, 512 threads (8 waves).
// A in registers; B streamed through 2x64KB LDS dbuf.
// CHANGE vs v3: cg covers a CONTIGUOUS tile range [cg*393/8, (cg+1)*393/8) instead
// of strided cg+it*8. Successive iterations write ADJACENT 512B segments of each
// prob row -> the misaligned 64B edge lines (row pitch 201028 = 4 mod 64) merge in
// the same XCD's L2 across iters, killing the 1.49x write amplification.
template <int PASS>
__global__ __launch_bounds__(512, 2) void big_gemm(
    const unsigned short* __restrict__ ebf,
    const unsigned short* __restrict__ embbf,
    const float* __restrict__ vbias,
    float* __restrict__ psum,
    const float* __restrict__ denom,
    float* __restrict__ prob) {
    __shared__ unsigned short sB[2][TN * 256];   // 128 KB

    int bid = blockIdx.x;
    int rt = bid >> 3;           // 32 row tiles
    int cg = bid & 7;            // col group == XCD
    int row0 = rt * 128;
    int tid = threadIdx.x;
    int wave = tid >> 6, lane = tid & 63;
    int l31 = lane & 31, hi = lane >> 5;
    int wr = wave >> 2, wc = wave & 3;
    int tstart = (cg * NCT3) / CG;
    int tend = ((cg + 1) * NCT3) / CG;
    int nmy = tend - tstart;

    bf16x8 a[2][16];
    {
        const unsigned short* ab =
            ebf + (size_t)(row0 + wr * 64 + l31) * 256 + hi * 8;
#pragma unroll
        for (int mf = 0; mf < 2; ++mf)
#pragma unroll
            for (int ks = 0; ks < 16; ++ks)
                a[mf][ks] = *reinterpret_cast<const bf16x8*>(ab + mf * 32 * 256 + ks * 16);
    }

    auto stage = [&](int ct, int buf) {
        int col0 = ct * TN;
#pragma unroll
        for (int i = 0; i < 8; ++i) {
            int col = i * 16 + wave * 2 + hi;
            int gcol = col0 + col; if (gcol >= VOC) gcol = VOC - 1;
            const unsigned short* src =
                embbf + (size_t)gcol * 256 + ((l31 ^ (col & 7)) * 8);
            unsigned short* dst = (unsigned short*)sB[buf] + (size_t)(i * 512 + wave * 64) * 8;
            __builtin_amdgcn_global_load_lds(
                (const __attribute__((address_space(1))) void*)src,
                (__attribute__((address_space(3))) void*)dst, 16, 0, 0);
        }
    };

    stage(tstart, 0);
    asm volatile("s_waitcnt vmcnt(0)" ::: "memory");
    __syncthreads();

    float invd[2][16];
    if (PASS == 1) {
#pragma unroll
        for (int mf = 0; mf < 2; ++mf)
#pragma unroll
            for (int r = 0; r < 16; ++r) {
                int row = row0 + wr * 64 + mf * 32 + (r & 3) + 8 * (r >> 2) + 4 * hi;
                invd[mf][r] = 1.f / denom[row];
            }
    }
    float es[2][16];
    if (PASS == 0) {
#pragma unroll
        for (int mf = 0; mf < 2; ++mf)
#pragma unroll
            for (int r = 0; r < 16; ++r) es[mf][r] = 0.f;
    }

    f32x16 zz = {0.f,0.f,0.f,0.f,0.f,0.f,0.f,0.f,0.f,0.f,0.f,0.f,0.f,0.f,0.f,0.f};

    for (int it = 0; it < nmy; ++it) {
        int ct = tstart + it;
        if (it + 1 < nmy) stage(ct + 1, (it + 1) & 1);

        int gc = ct * TN + wc * 32 + l31;
        float bvb;
        if (PASS == 0) bvb = (gc < VOC) ? vbias[gc] : -1e4f;
        else           bvb = vbias[(gc < VOC) ? gc : (VOC - 1)];

        const unsigned short* sBc = (const unsigned short*)sB[it & 1];
        int bcol = wc * 32 + l31;
        f32x16 c0 = zz, c1 = zz;
#pragma unroll
        for (int ks = 0; ks < 16; ++ks) {
            int kc = ks * 2 + hi;
            bf16x8 b = *reinterpret_cast<const bf16x8*>(
                sBc + bcol * 256 + ((kc ^ (bcol & 7)) * 8));
            c0 = __builtin_amdgcn_mfma_f32_32x32x16_bf16(a[0][ks], b, c0, 0, 0, 0);
            c1 = __builtin_amdgcn_mfma_f32_32x32x16_bf16(a[1][ks], b, c1, 0, 0, 0);
        }

        asm volatile("s_waitcnt vmcnt(0)" ::: "memory");
        __syncthreads();

        if (PASS == 0) {
#pragma unroll
            for (int r = 0; r < 16; ++r) {
                es[0][r] += __expf(c0[r] + bvb);
                es[1][r] += __expf(c1[r] + bvb);
            }
        } else {
            if (gc < VOC) {
#pragma unroll
                for (int r = 0; r < 16; ++r) {
                    int rowr = row0 + wr * 64 + (r & 3) + 8 * (r >> 2) + 4 * hi;
                    prob[(size_t)rowr * VOC + gc] = __expf(c0[r] + bvb) * invd[0][r];
                    prob[(size_t)(rowr + 32) * VOC + gc] = __expf(c1[r] + bvb) * invd[1][r];
                }
            }
        }
    }

    if (PASS == 0) {
#pragma unroll
        for (int mf = 0; mf < 2; ++mf)
#pragma unroll
            for (int r = 0; r < 16; ++r) {
                float v = es[mf][r];
#pragma unroll
                for (int off = 1; off < 32; off <<= 1) v += __shfl_xor(v, off);
                if (l31 == 0) {
                    int row = row0 + wr * 64 + mf * 32 + (r & 3) + 8 * (r >> 2) + 4 * hi;
                    psum[(size_t)row * 32 + cg * 4 + wc] = v;
                }
            }
    }
}

// ---------------------------------------------------------------- finalize: denom + loss
__global__ __launch_bounds__(64) void finalize_k(
    const float* __restrict__ psum,
    const unsigned short* __restrict__ ebf, const unsigned short* __restrict__ embbf,
    const float* __restrict__ vbias, const int* __restrict__ labels,
    float* __restrict__ denom, float* __restrict__ loss) {
    int n = blockIdx.x, lane = threadIdx.x;
    float s = (lane < 32) ? psum[(size_t)n * 32 + lane] : 0.f;
#pragma unroll
    for (int off = 1; off < 32; off <<= 1) s += __shfl_xor(s, off);
    int lf = labels[n];
    const unsigned short* ev = ebf + n * 256;
    const unsigned short* mv = embbf + (size_t)lf * 256;
    float p = 0.f;
#pragma unroll
    for (int i = 0; i < 4; ++i) p += bf2f(ev[lane * 4 + i]) * bf2f(mv[lane * 4 + i]);
#pragma unroll
    for (int off = 1; off < 64; off <<= 1) p += __shfl_xor(p, off);
    if (lane == 0) {
        denom[n] = s;
        loss[n] = logf(s) - (p + vbias[lf]);
    }
}

// ---------------------------------------------------------------- launch
extern "C" void kernel_launch(void* const* d_in, const int* in_sizes, int n_in,
                              void* d_out, int out_size, void* d_ws, size_t ws_size,
                              hipStream_t stream) {
    const float* x      = (const float*)d_in[0];
    const int*   labels = (const int*)d_in[1];
    const int*   xb     = (const int*)d_in[2];
    const float* Wsh    = (const float*)d_in[3];
    const float* bsh    = (const float*)d_in[4];
    const float* Wsp    = (const float*)d_in[5];
    const float* bsp    = (const float*)d_in[6];
    const float* wg     = (const float*)d_in[7];
    const float* vbias  = (const float*)d_in[8];
    const float* emb    = (const float*)d_in[9];
    const float* gamma  = (const float*)d_in[10];
    const float* beta   = (const float*)d_in[11];

    char* ws = (char*)d_ws;
    unsigned short* embbf = (unsigned short*)(ws + 2097152);    // 25,731,584
    unsigned short* Wtbf  = (unsigned short*)(ws + 27828736);   // 1,310,720
    float* cexp           = (float*)(ws + 29360128);            // 41,943,040
    unsigned short* ebf   = (unsigned short*)(ws + 71303168);   // 2,097,152
    float* psum           = (float*)(ws + 73400320);            // 524,288
    float* denom          = (float*)(ws + 73924608);            // 16,384

    float* prob = (float*)d_out;
    float* loss = prob + PROB_ELEMS;

    prep_kernel<<<dim3(2208), dim3(256), 0, stream>>>(emb, Wsh, Wsp, embbf, Wtbf);
    expert_gemm<<<dim3(64 * 40), dim3(256), 0, stream>>>(x, Wtbf, bsh, bsp, cexp);
    combine_ln<<<dim3(NTOK), dim3(256), 0, stream>>>(x, xb, wg, cexp, gamma, beta, ebf);
    big_gemm<0><<<dim3(256), dim3(512), 0, stream>>>(ebf, embbf, vbias, psum, nullptr, nullptr);
    finalize_k<<<dim3(NTOK), dim3(64), 0, stream>>>(psum, ebf, embbf, vbias, labels, denom, loss);
    big_gemm<1><<<dim3(256), dim3(512), 0, stream>>>(ebf, embbf, vbias, nullptr, denom, prob);
}